// Round 3
// baseline (172.054 us; speedup 1.0000x reference)
//
#include <hip/hip_runtime.h>
#include <math.h>

// Performer FAVOR+ feature map — SINGLE kernel (R14 = R12 with the
// nontemporal-store compile fix: __builtin_nontemporal_store needs a clang
// ext-vector pointer (f32x4*), not HIP_vector_type float4*).
//   out[t][j] = ratio*(exp( x[t].(nrm*proj[j]) - 0.5*||x[t]||^2 ) + eps)
//             = exp2( acc*log2e + dlog[t] ) + ratio*eps
//   dlog[t] = -0.5*||x[t]||^2*log2e - 4   (ratio=2^-4 folded into exponent)
//   bf16 hi/lo 3-term MFMA (drop lo*lo; absmax 3e-8, verified R2..R11).
//
// R12/R14 delta vs R11 (158.1/159.0): MFMA called as mfma(P, X) instead of
// mfma(X, P). A and B operands share the same (lane,elem)->(idx,k) fragment
// map, so the frags are unchanged; but C now has col=token (li), row=feat
// (q*4+reg) -> each lane owns 4 CONSECUTIVE feats of one token. Epilogue
// becomes ONE nontemporal global_store_dwordx4 per (tt,nf) instead of 4
// scalar dword stores: 16 store instrs/wave/block vs 64, 1024B/instr vs
// 256B. Theory: kernel is ~3x off the 6.7 TB/s write roofline (the harness
// fill proves the BW) with near-idle compute pipes; scalar store issue/width
// is the remaining fat. dl also becomes a scalar broadcast (token=li).
//
// Main: 512 thr = 8 waves, tile 128 tokens x 256 feats.
//   Stage: wave w cvts its 16 tokens -> hi/lo bf16 x-frags in LDS (32 KB,
//   conflict-free ds_write_b128), dlog via 2 shfl. One barrier.
//   Compute: wave w owns feats [32w,32w+32): 8 token tiles x
//   { 4 ds_read_b128 + 12 MFMA + 8 exp2 + 2 dwordx4 nt stores }.

typedef short bf16x8 __attribute__((ext_vector_type(8)));
typedef float f32x4  __attribute__((ext_vector_type(4)));

__device__ __forceinline__ unsigned short f2bf_rne(float f) {
    unsigned u = __builtin_bit_cast(unsigned, f);
    unsigned r = u + 0x7FFFu + ((u >> 16) & 1u);
    return (unsigned short)(r >> 16);
}

__device__ __forceinline__ void f2bf_hilo(float f, unsigned short& h, unsigned short& l) {
    h = f2bf_rne(f);
    float fh = __builtin_bit_cast(float, (unsigned)h << 16);
    l = f2bf_rne(f - fh);
}

__global__ __launch_bounds__(512, 4)
void performer_fm_kernel(const float* __restrict__ x,
                         const float* __restrict__ proj,
                         float* __restrict__ out) {
    // x frags: 8 tt x 4 frags(h0,l0,h1,l1) x 64 lanes x 16 B = 32 KB
    __shared__ __align__(16) short Af[8 * 4 * 64 * 8];
    __shared__ float dlg[128];

    const int wave = threadIdx.x >> 6;
    const int lane = threadIdx.x & 63;
    const int q    = lane >> 4;
    const int li   = lane & 15;
    const long t0  = (long)blockIdx.x * 128;

    // ---- staging: wave w -> tokens [t0+16w, t0+16w+16) ----
    const float4* xr = (const float4*)(x + (t0 + wave * 16 + li) * 64);
    float4 a0 = xr[q * 2];          // k = q*8 .. q*8+3
    float4 a1 = xr[q * 2 + 1];      // k = q*8+4 .. q*8+7
    float4 a2 = xr[8 + q * 2];      // k = 32+q*8 ..
    float4 a3 = xr[8 + q * 2 + 1];

    // ---- proj fragments built in-register (L2-hot, overlaps x latency) ----
    // frag elem j of (nf,kc): proj[(wave*2+nf)*16+li][kc*32+q*8+j] * nrm
    bf16x8 Ph[2][2], Pl[2][2];
    {
        const float nrm = 0.35355339059327373f;  // 64^-0.25
        #pragma unroll
        for (int nf = 0; nf < 2; ++nf) {
            const int n = (wave * 2 + nf) * 16 + li;
            #pragma unroll
            for (int kc = 0; kc < 2; ++kc) {
                const int kb = kc * 32 + q * 8;
                float4 v0 = *(const float4*)&proj[n * 64 + kb];
                float4 v1 = *(const float4*)&proj[n * 64 + kb + 4];
                float vals[8] = {v0.x, v0.y, v0.z, v0.w, v1.x, v1.y, v1.z, v1.w};
                union { unsigned short us[8]; bf16x8 v; } hh, ll;
                #pragma unroll
                for (int j = 0; j < 8; ++j)
                    f2bf_hilo(vals[j] * nrm, hh.us[j], ll.us[j]);
                Ph[nf][kc] = hh.v;
                Pl[nf][kc] = ll.v;
            }
        }
    }

    // exact fp32 ||x||^2 for token (16w+li): reduce across q groups
    float p = a0.x * a0.x + a0.y * a0.y + a0.z * a0.z + a0.w * a0.w
            + a1.x * a1.x + a1.y * a1.y + a1.z * a1.z + a1.w * a1.w
            + a2.x * a2.x + a2.y * a2.y + a2.z * a2.z + a2.w * a2.w
            + a3.x * a3.x + a3.y * a3.y + a3.z * a3.z + a3.w * a3.w;
    p += __shfl_xor(p, 16);
    p += __shfl_xor(p, 32);
    const float NHL2E = -0.7213475204444817f;    // -0.5*log2(e)
    if (q == 0) dlg[wave * 16 + li] = fmaf(NHL2E, p, -4.0f);

    // register hi/lo pack -> LDS frags (conflict-free b128 at base+lane*16)
    {
        float v0[8] = {a0.x, a0.y, a0.z, a0.w, a1.x, a1.y, a1.z, a1.w};
        float v1[8] = {a2.x, a2.y, a2.z, a2.w, a3.x, a3.y, a3.z, a3.w};
        union { unsigned short us[8]; bf16x8 v; } h0, l0, h1, l1;
        #pragma unroll
        for (int j = 0; j < 8; ++j) {
            f2bf_hilo(v0[j], h0.us[j], l0.us[j]);
            f2bf_hilo(v1[j], h1.us[j], l1.us[j]);
        }
        bf16x8* As = (bf16x8*)Af;
        const int base = wave * 4 * 64 + lane;   // tt = wave
        As[base]       = h0.v;
        As[base + 64]  = l0.v;
        As[base + 128] = h1.v;
        As[base + 192] = l1.v;
    }
    __syncthreads();

    const bf16x8* As = (const bf16x8*)Af;
    const float LOG2E = 1.4426950408889634f;
    const float REPS  = 6.25e-6f;                // ratio*eps

    #pragma unroll 2
    for (int tt = 0; tt < 8; ++tt) {
        const int ab = tt * 256 + lane;
        bf16x8 xh0 = As[ab];
        bf16x8 xl0 = As[ab + 64];
        bf16x8 xh1 = As[ab + 128];
        bf16x8 xl1 = As[ab + 192];
        const float dl = dlg[tt * 16 + li];      // token = li now (broadcast)

        // lane (q,li), tile (tt,nf): C col = li -> token t0+tt*16+li,
        // C row = q*4+r -> feat wave*32 + nf*16 + q*4 + r  => f32x4 store.
        f32x4* ob = (f32x4*)(out + (t0 + tt * 16 + li) * 256 + wave * 32 + q * 4);
        #pragma unroll
        for (int nf = 0; nf < 2; ++nf) {
            f32x4 acc = {0.f, 0.f, 0.f, 0.f};
            acc = __builtin_amdgcn_mfma_f32_16x16x32_bf16(Ph[nf][0], xl0, acc, 0, 0, 0);
            acc = __builtin_amdgcn_mfma_f32_16x16x32_bf16(Pl[nf][0], xh0, acc, 0, 0, 0);
            acc = __builtin_amdgcn_mfma_f32_16x16x32_bf16(Ph[nf][0], xh0, acc, 0, 0, 0);
            acc = __builtin_amdgcn_mfma_f32_16x16x32_bf16(Ph[nf][1], xl1, acc, 0, 0, 0);
            acc = __builtin_amdgcn_mfma_f32_16x16x32_bf16(Pl[nf][1], xh1, acc, 0, 0, 0);
            acc = __builtin_amdgcn_mfma_f32_16x16x32_bf16(Ph[nf][1], xh1, acc, 0, 0, 0);
            f32x4 o;
            o[0] = __builtin_amdgcn_exp2f(fmaf(acc[0], LOG2E, dl)) + REPS;
            o[1] = __builtin_amdgcn_exp2f(fmaf(acc[1], LOG2E, dl)) + REPS;
            o[2] = __builtin_amdgcn_exp2f(fmaf(acc[2], LOG2E, dl)) + REPS;
            o[3] = __builtin_amdgcn_exp2f(fmaf(acc[3], LOG2E, dl)) + REPS;
            __builtin_nontemporal_store(o, ob + nf * 4);   // +nf*16 floats
        }
    }
}

extern "C" void kernel_launch(void* const* d_in, const int* in_sizes, int n_in,
                              void* d_out, int out_size, void* d_ws, size_t ws_size,
                              hipStream_t stream) {
    const float* x    = (const float*)d_in[0];
    const float* proj = (const float*)d_in[1];
    float* out        = (float*)d_out;
    const int ntok    = in_sizes[0] / 64;        // 131072

    performer_fm_kernel<<<ntok / 128, 512, 0, stream>>>(x, proj, out);
}

// Round 4
// 162.338 us; speedup vs baseline: 1.0599x; 1.0599x over previous
//
#include <hip/hip_runtime.h>
#include <math.h>

// Performer FAVOR+ feature map — SINGLE kernel (R15 = R14 minus the
// nontemporal hint; plain f32x4 store through L2).
//   out[t][j] = ratio*(exp( x[t].(nrm*proj[j]) - 0.5*||x[t]||^2 ) + eps)
//             = exp2( acc*log2e + dlog[t] ) + ratio*eps
//   dlog[t] = -0.5*||x[t]||^2*log2e - 4   (ratio=2^-4 folded into exponent)
//   bf16 hi/lo 3-term MFMA (drop lo*lo; absmax 3e-8, verified R2..R14).
//
// R14 post-mortem (172.0 vs R11 159.0): regression = ~3.5% chip-clock window
// (fill BW 6.52 vs 6.70-6.81 TB/s) + the nt store flag. Segment analysis:
// swapped-operand f32x4 stores have the SAME 256x64B-segment pattern per
// wave-block as R11's scalar stores (16 segs x 16 instrs vs 4 segs x 64),
// so the swap is ~neutral at the transaction level; but `nt` bypasses L2
// write-combining and is the only mechanism in the diff that loses real BW.
// R15 keeps the swap (fewer instrs, dl scalar broadcast) and drops nt.
//
// Main: 512 thr = 8 waves, tile 128 tokens x 256 feats.
//   Stage: wave w cvts its 16 tokens -> hi/lo bf16 x-frags in LDS (32 KB,
//   conflict-free ds_write_b128), dlog via 2 shfl. One barrier.
//   Compute: wave w owns feats [32w,32w+32): 8 token tiles x
//   { 4 ds_read_b128 + 12 MFMA + 8 exp2 + 2 dwordx4 stores }.

typedef short bf16x8 __attribute__((ext_vector_type(8)));
typedef float f32x4  __attribute__((ext_vector_type(4)));

__device__ __forceinline__ unsigned short f2bf_rne(float f) {
    unsigned u = __builtin_bit_cast(unsigned, f);
    unsigned r = u + 0x7FFFu + ((u >> 16) & 1u);
    return (unsigned short)(r >> 16);
}

__device__ __forceinline__ void f2bf_hilo(float f, unsigned short& h, unsigned short& l) {
    h = f2bf_rne(f);
    float fh = __builtin_bit_cast(float, (unsigned)h << 16);
    l = f2bf_rne(f - fh);
}

__global__ __launch_bounds__(512, 4)
void performer_fm_kernel(const float* __restrict__ x,
                         const float* __restrict__ proj,
                         float* __restrict__ out) {
    // x frags: 8 tt x 4 frags(h0,l0,h1,l1) x 64 lanes x 16 B = 32 KB
    __shared__ __align__(16) short Af[8 * 4 * 64 * 8];
    __shared__ float dlg[128];

    const int wave = threadIdx.x >> 6;
    const int lane = threadIdx.x & 63;
    const int q    = lane >> 4;
    const int li   = lane & 15;
    const long t0  = (long)blockIdx.x * 128;

    // ---- staging: wave w -> tokens [t0+16w, t0+16w+16) ----
    const float4* xr = (const float4*)(x + (t0 + wave * 16 + li) * 64);
    float4 a0 = xr[q * 2];          // k = q*8 .. q*8+3
    float4 a1 = xr[q * 2 + 1];      // k = q*8+4 .. q*8+7
    float4 a2 = xr[8 + q * 2];      // k = 32+q*8 ..
    float4 a3 = xr[8 + q * 2 + 1];

    // ---- proj fragments built in-register (L2-hot, overlaps x latency) ----
    // frag elem j of (nf,kc): proj[(wave*2+nf)*16+li][kc*32+q*8+j] * nrm
    bf16x8 Ph[2][2], Pl[2][2];
    {
        const float nrm = 0.35355339059327373f;  // 64^-0.25
        #pragma unroll
        for (int nf = 0; nf < 2; ++nf) {
            const int n = (wave * 2 + nf) * 16 + li;
            #pragma unroll
            for (int kc = 0; kc < 2; ++kc) {
                const int kb = kc * 32 + q * 8;
                float4 v0 = *(const float4*)&proj[n * 64 + kb];
                float4 v1 = *(const float4*)&proj[n * 64 + kb + 4];
                float vals[8] = {v0.x, v0.y, v0.z, v0.w, v1.x, v1.y, v1.z, v1.w};
                union { unsigned short us[8]; bf16x8 v; } hh, ll;
                #pragma unroll
                for (int j = 0; j < 8; ++j)
                    f2bf_hilo(vals[j] * nrm, hh.us[j], ll.us[j]);
                Ph[nf][kc] = hh.v;
                Pl[nf][kc] = ll.v;
            }
        }
    }

    // exact fp32 ||x||^2 for token (16w+li): reduce across q groups
    float p = a0.x * a0.x + a0.y * a0.y + a0.z * a0.z + a0.w * a0.w
            + a1.x * a1.x + a1.y * a1.y + a1.z * a1.z + a1.w * a1.w
            + a2.x * a2.x + a2.y * a2.y + a2.z * a2.z + a2.w * a2.w
            + a3.x * a3.x + a3.y * a3.y + a3.z * a3.z + a3.w * a3.w;
    p += __shfl_xor(p, 16);
    p += __shfl_xor(p, 32);
    const float NHL2E = -0.7213475204444817f;    // -0.5*log2(e)
    if (q == 0) dlg[wave * 16 + li] = fmaf(NHL2E, p, -4.0f);

    // register hi/lo pack -> LDS frags (conflict-free b128 at base+lane*16)
    {
        float v0[8] = {a0.x, a0.y, a0.z, a0.w, a1.x, a1.y, a1.z, a1.w};
        float v1[8] = {a2.x, a2.y, a2.z, a2.w, a3.x, a3.y, a3.z, a3.w};
        union { unsigned short us[8]; bf16x8 v; } h0, l0, h1, l1;
        #pragma unroll
        for (int j = 0; j < 8; ++j) {
            f2bf_hilo(v0[j], h0.us[j], l0.us[j]);
            f2bf_hilo(v1[j], h1.us[j], l1.us[j]);
        }
        bf16x8* As = (bf16x8*)Af;
        const int base = wave * 4 * 64 + lane;   // tt = wave
        As[base]       = h0.v;
        As[base + 64]  = l0.v;
        As[base + 128] = h1.v;
        As[base + 192] = l1.v;
    }
    __syncthreads();

    const bf16x8* As = (const bf16x8*)Af;
    const float LOG2E = 1.4426950408889634f;
    const float REPS  = 6.25e-6f;                // ratio*eps

    #pragma unroll 2
    for (int tt = 0; tt < 8; ++tt) {
        const int ab = tt * 256 + lane;
        bf16x8 xh0 = As[ab];
        bf16x8 xl0 = As[ab + 64];
        bf16x8 xh1 = As[ab + 128];
        bf16x8 xl1 = As[ab + 192];
        const float dl = dlg[tt * 16 + li];      // token = li (broadcast)

        // lane (q,li), tile (tt,nf): C col = li -> token t0+tt*16+li,
        // C row = q*4+r -> feat wave*32 + nf*16 + q*4 + r  => f32x4 store.
        f32x4* ob = (f32x4*)(out + (t0 + tt * 16 + li) * 256 + wave * 32 + q * 4);
        #pragma unroll
        for (int nf = 0; nf < 2; ++nf) {
            f32x4 acc = {0.f, 0.f, 0.f, 0.f};
            acc = __builtin_amdgcn_mfma_f32_16x16x32_bf16(Ph[nf][0], xl0, acc, 0, 0, 0);
            acc = __builtin_amdgcn_mfma_f32_16x16x32_bf16(Pl[nf][0], xh0, acc, 0, 0, 0);
            acc = __builtin_amdgcn_mfma_f32_16x16x32_bf16(Ph[nf][0], xh0, acc, 0, 0, 0);
            acc = __builtin_amdgcn_mfma_f32_16x16x32_bf16(Ph[nf][1], xl1, acc, 0, 0, 0);
            acc = __builtin_amdgcn_mfma_f32_16x16x32_bf16(Pl[nf][1], xh1, acc, 0, 0, 0);
            acc = __builtin_amdgcn_mfma_f32_16x16x32_bf16(Ph[nf][1], xh1, acc, 0, 0, 0);
            f32x4 o;
            o[0] = __builtin_amdgcn_exp2f(fmaf(acc[0], LOG2E, dl)) + REPS;
            o[1] = __builtin_amdgcn_exp2f(fmaf(acc[1], LOG2E, dl)) + REPS;
            o[2] = __builtin_amdgcn_exp2f(fmaf(acc[2], LOG2E, dl)) + REPS;
            o[3] = __builtin_amdgcn_exp2f(fmaf(acc[3], LOG2E, dl)) + REPS;
            ob[nf * 4] = o;                      // +nf*16 floats
        }
    }
}

extern "C" void kernel_launch(void* const* d_in, const int* in_sizes, int n_in,
                              void* d_out, int out_size, void* d_ws, size_t ws_size,
                              hipStream_t stream) {
    const float* x    = (const float*)d_in[0];
    const float* proj = (const float*)d_in[1];
    float* out        = (float*)d_out;
    const int ntok    = in_sizes[0] / 64;        // 131072

    performer_fm_kernel<<<ntok / 128, 512, 0, stream>>>(x, proj, out);
}

// Round 14
// 160.349 us; speedup vs baseline: 1.0730x; 1.0124x over previous
//
#include <hip/hip_runtime.h>
#include <math.h>

// Performer FAVOR+ feature map — SINGLE kernel (R25 = R16 resubmitted
// unchanged: R16..R24 benches never ran — GPUAcquisitionTimeout x9).
// R16 = R15 + LDS-transposed epilogue producing FULL-CACHE-LINE stores.
//   out[t][j] = ratio*(exp( x[t].(nrm*proj[j]) - 0.5*||x[t]||^2 ) + eps)
//             = exp2( acc*log2e + dlog[t] ) + ratio*eps
//   bf16 hi/lo 3-term MFMA (drop lo*lo; absmax 3e-8, verified R2..R15).
//
// R15 post-mortem: R11(159.0) vs R15(162.3) at matched clock -> the operand
// swap was neutral: BOTH epilogues store 64B half-lines at 1KB stride (4
// lanes x 16B). Kernel inferred 55-78us vs a 25us traffic floor while the
// harness fill proves 6.8 TB/s on this buffer with full-line stores. Theory:
// partial-line write misses trigger L2 read-for-ownership (+~134MB hidden
// FETCH, RMW serialization) = the 2-3x gap; also explains nt regression.
//
// R16: per token-tile tt, waves write exp'd accs to a 16KB LDS Ebuf
// (XOR-swizzled, bank-minimal), ONE raw s_barrier (lgkmcnt only — NOT
// __syncthreads, which drains vmcnt and would expose store latency 8x),
// then 512 threads read back row-major and store 512B-contiguous full-line
// segments (2 f32x4/thread = whole token rows, same shape as the 6.8TB/s
// fill). Ebuf double-buffered (2x16KB) -> 1 barrier/tt is reuse-safe
// (lgkmcnt(0) before barrier covers both this tt's writes and last tt's
// reads; buf[p] is rewritten two barriers after its read).
// LDS 64.5KB total, still 2 blocks/CU. Epilogue is bit-exact pass-through.
//
// Main: 512 thr = 8 waves, tile 128 tokens x 256 feats.
//   Stage: wave w cvts its 16 tokens -> hi/lo bf16 x-frags in LDS (32 KB,
//   conflict-free ds_write_b128), dlog via 2 shfl. One barrier.
//   Compute: wave w owns feats [32w,32w+32): 8 token tiles x
//   { 4 ds_read_b128 + 12 MFMA + 8 exp2 + LDS transpose + 2 full-line stores }.

typedef short bf16x8 __attribute__((ext_vector_type(8)));
typedef float f32x4  __attribute__((ext_vector_type(4)));

__device__ __forceinline__ unsigned short f2bf_rne(float f) {
    unsigned u = __builtin_bit_cast(unsigned, f);
    unsigned r = u + 0x7FFFu + ((u >> 16) & 1u);
    return (unsigned short)(r >> 16);
}

__device__ __forceinline__ void f2bf_hilo(float f, unsigned short& h, unsigned short& l) {
    h = f2bf_rne(f);
    float fh = __builtin_bit_cast(float, (unsigned)h << 16);
    l = f2bf_rne(f - fh);
}

__global__ __launch_bounds__(512, 4)
void performer_fm_kernel(const float* __restrict__ x,
                         const float* __restrict__ proj,
                         float* __restrict__ out) {
    // x frags: 8 tt x 4 frags(h0,l0,h1,l1) x 64 lanes x 16 B = 32 KB
    __shared__ __align__(16) short Af[8 * 4 * 64 * 8];
    // epilogue transpose buffer: 2 x 16 tokens x 256 feats x 4 B = 32 KB
    __shared__ __align__(16) float Eb[2 * 16 * 256];
    __shared__ float dlg[128];

    const int wave = threadIdx.x >> 6;
    const int lane = threadIdx.x & 63;
    const int q    = lane >> 4;
    const int li   = lane & 15;
    const long t0  = (long)blockIdx.x * 128;

    // ---- staging: wave w -> tokens [t0+16w, t0+16w+16) ----
    const float4* xr = (const float4*)(x + (t0 + wave * 16 + li) * 64);
    float4 a0 = xr[q * 2];          // k = q*8 .. q*8+3
    float4 a1 = xr[q * 2 + 1];      // k = q*8+4 .. q*8+7
    float4 a2 = xr[8 + q * 2];      // k = 32+q*8 ..
    float4 a3 = xr[8 + q * 2 + 1];

    // ---- proj fragments built in-register (L2-hot, overlaps x latency) ----
    // frag elem j of (nf,kc): proj[(wave*2+nf)*16+li][kc*32+q*8+j] * nrm
    bf16x8 Ph[2][2], Pl[2][2];
    {
        const float nrm = 0.35355339059327373f;  // 64^-0.25
        #pragma unroll
        for (int nf = 0; nf < 2; ++nf) {
            const int n = (wave * 2 + nf) * 16 + li;
            #pragma unroll
            for (int kc = 0; kc < 2; ++kc) {
                const int kb = kc * 32 + q * 8;
                float4 v0 = *(const float4*)&proj[n * 64 + kb];
                float4 v1 = *(const float4*)&proj[n * 64 + kb + 4];
                float vals[8] = {v0.x, v0.y, v0.z, v0.w, v1.x, v1.y, v1.z, v1.w};
                union { unsigned short us[8]; bf16x8 v; } hh, ll;
                #pragma unroll
                for (int j = 0; j < 8; ++j)
                    f2bf_hilo(vals[j] * nrm, hh.us[j], ll.us[j]);
                Ph[nf][kc] = hh.v;
                Pl[nf][kc] = ll.v;
            }
        }
    }

    // exact fp32 ||x||^2 for token (16w+li): reduce across q groups
    float p = a0.x * a0.x + a0.y * a0.y + a0.z * a0.z + a0.w * a0.w
            + a1.x * a1.x + a1.y * a1.y + a1.z * a1.z + a1.w * a1.w
            + a2.x * a2.x + a2.y * a2.y + a2.z * a2.z + a2.w * a2.w
            + a3.x * a3.x + a3.y * a3.y + a3.z * a3.z + a3.w * a3.w;
    p += __shfl_xor(p, 16);
    p += __shfl_xor(p, 32);
    const float NHL2E = -0.7213475204444817f;    // -0.5*log2(e)
    if (q == 0) dlg[wave * 16 + li] = fmaf(NHL2E, p, -4.0f);

    // register hi/lo pack -> LDS frags (conflict-free b128 at base+lane*16)
    {
        float v0[8] = {a0.x, a0.y, a0.z, a0.w, a1.x, a1.y, a1.z, a1.w};
        float v1[8] = {a2.x, a2.y, a2.z, a2.w, a3.x, a3.y, a3.z, a3.w};
        union { unsigned short us[8]; bf16x8 v; } h0, l0, h1, l1;
        #pragma unroll
        for (int j = 0; j < 8; ++j) {
            f2bf_hilo(v0[j], h0.us[j], l0.us[j]);
            f2bf_hilo(v1[j], h1.us[j], l1.us[j]);
        }
        bf16x8* As = (bf16x8*)Af;
        const int base = wave * 4 * 64 + lane;   // tt = wave
        As[base]       = h0.v;
        As[base + 64]  = l0.v;
        As[base + 128] = h1.v;
        As[base + 192] = l1.v;
    }
    __syncthreads();

    const bf16x8* As = (const bf16x8*)Af;
    char* Ebc = (char*)Eb;
    const float LOG2E = 1.4426950408889634f;
    const float REPS  = 6.25e-6f;                // ratio*eps

    const int row = threadIdx.x >> 5;            // epilogue-read row 0..15
    const int c   = threadIdx.x & 31;            // epilogue-read col quad

    #pragma unroll 2
    for (int tt = 0; tt < 8; ++tt) {
        const int ab = tt * 256 + lane;
        bf16x8 xh0 = As[ab];
        bf16x8 xl0 = As[ab + 64];
        bf16x8 xh1 = As[ab + 128];
        bf16x8 xl1 = As[ab + 192];
        const float dl = dlg[tt * 16 + li];      // token = li (broadcast)

        const int ebase = (tt & 1) * 16384;      // double-buffer half (bytes)

        // lane (q,li), tile nf: C col = li -> token-local row li,
        // C row = q*4+r -> feat wave*32 + nf*16 + q*4 + r.
        // Write f32x4 into Ebuf[li][feat] with XOR swizzle ((li&7)<<4):
        // per-instr banks get exactly 8 accesses each (minimal for 1KB).
        #pragma unroll
        for (int nf = 0; nf < 2; ++nf) {
            f32x4 acc = {0.f, 0.f, 0.f, 0.f};
            acc = __builtin_amdgcn_mfma_f32_16x16x32_bf16(Ph[nf][0], xl0, acc, 0, 0, 0);
            acc = __builtin_amdgcn_mfma_f32_16x16x32_bf16(Pl[nf][0], xh0, acc, 0, 0, 0);
            acc = __builtin_amdgcn_mfma_f32_16x16x32_bf16(Ph[nf][0], xh0, acc, 0, 0, 0);
            acc = __builtin_amdgcn_mfma_f32_16x16x32_bf16(Ph[nf][1], xl1, acc, 0, 0, 0);
            acc = __builtin_amdgcn_mfma_f32_16x16x32_bf16(Pl[nf][1], xh1, acc, 0, 0, 0);
            acc = __builtin_amdgcn_mfma_f32_16x16x32_bf16(Ph[nf][1], xh1, acc, 0, 0, 0);
            f32x4 o;
            o[0] = __builtin_amdgcn_exp2f(fmaf(acc[0], LOG2E, dl)) + REPS;
            o[1] = __builtin_amdgcn_exp2f(fmaf(acc[1], LOG2E, dl)) + REPS;
            o[2] = __builtin_amdgcn_exp2f(fmaf(acc[2], LOG2E, dl)) + REPS;
            o[3] = __builtin_amdgcn_exp2f(fmaf(acc[3], LOG2E, dl)) + REPS;
            const int wb = ebase + li * 1024 +
                (((wave * 128) + nf * 64 + q * 16) ^ ((li & 7) << 4));
            *(f32x4*)(Ebc + wb) = o;
        }

        // raw barrier: ds_writes visible (lgkmcnt 0), but do NOT drain vmcnt
        // (in-flight global stores from previous tt keep streaming).
        asm volatile("s_waitcnt lgkmcnt(0)" ::: "memory");
        __builtin_amdgcn_s_barrier();
        __builtin_amdgcn_sched_barrier(0);

        // read back row-major; store 512B-contiguous full-line segments.
        {
            const int rb = ebase + row * 1024;
            f32x4 r0 = *(const f32x4*)(Ebc + rb + ((c * 16) ^ ((row & 7) << 4)));
            f32x4 r1 = *(const f32x4*)(Ebc + rb + (((c * 16) + 512) ^ ((row & 7) << 4)));
            float* orow = out + (t0 + tt * 16 + row) * 256 + c * 4;
            *(f32x4*)orow = r0;
            *(f32x4*)(orow + 128) = r1;
        }
    }
}

extern "C" void kernel_launch(void* const* d_in, const int* in_sizes, int n_in,
                              void* d_out, int out_size, void* d_ws, size_t ws_size,
                              hipStream_t stream) {
    const float* x    = (const float*)d_in[0];
    const float* proj = (const float*)d_in[1];
    float* out        = (float*)d_out;
    const int ntok    = in_sizes[0] / 64;        // 131072

    performer_fm_kernel<<<ntok / 128, 512, 0, stream>>>(x, proj, out);
}